// Round 1
// baseline (573.483 us; speedup 1.0000x reference)
//
#include <hip/hip_runtime.h>
#include <hip/hip_bf16.h>
#include <stdint.h>

typedef short short8 __attribute__((ext_vector_type(8)));
typedef float f32x4 __attribute__((ext_vector_type(4)));
typedef float float4v __attribute__((ext_vector_type(4)));

#define KDIM 4096
#define TDIM 11008
#define BDIM 4096
#define KP 512  // KDIM/8 rows of qweight

// round-to-nearest-even f32 -> bf16 bits
static __device__ __forceinline__ unsigned short f2bf(float f) {
  unsigned u = __builtin_bit_cast(unsigned, f);
  u += 0x7FFFu + ((u >> 16) & 1u);
  return (unsigned short)(u >> 16);
}

// ---------------- kernel 1: dequant int4 -> bf16, transposed Wt[T][K] ----------------
// thread handles 4 consecutive qweight rows (32 consecutive k) at one t -> 64B contiguous store
__global__ __launch_bounds__(256) void dequant_k(const unsigned* __restrict__ qw,
                                                 const float* __restrict__ scales,
                                                 const float* __restrict__ zeros,
                                                 unsigned short* __restrict__ wt) {
  int idx = blockIdx.x * 256 + threadIdx.x;  // < (KP/4)*TDIM = 1,409,024 (grid exact)
  int rb = idx / TDIM;                       // 0..127
  int t = idx - rb * TDIM;
  int r0 = rb * 4;
  int g = rb >> 2;  // group = (r0*8)/128 = r0/16
  float s = scales[(size_t)g * TDIM + t];
  float z = zeros[(size_t)g * TDIM + t];
  float nzs = -z * s;
#pragma unroll
  for (int c = 0; c < 4; ++c) {
    unsigned q = qw[(size_t)(r0 + c) * TDIM + t];
    short8 o;
#pragma unroll
    for (int i = 0; i < 8; ++i) {
      float w = fmaf((float)((q >> (4 * i)) & 0xFu), s, nzs);
      o[i] = (short)f2bf(w);
    }
    *(short8*)(wt + (size_t)t * KDIM + (r0 + c) * 8) = o;
  }
}

// ---------------- kernel 2: x f32 -> bf16 ----------------
__global__ __launch_bounds__(256) void cvtx_k(const float* __restrict__ x,
                                              unsigned short* __restrict__ xb) {
  size_t i = ((size_t)blockIdx.x * 256 + threadIdx.x) * 8;
  float4v a = *(const float4v*)(x + i);
  float4v b = *(const float4v*)(x + i + 4);
  short8 o;
  o[0] = (short)f2bf(a[0]); o[1] = (short)f2bf(a[1]);
  o[2] = (short)f2bf(a[2]); o[3] = (short)f2bf(a[3]);
  o[4] = (short)f2bf(b[0]); o[5] = (short)f2bf(b[1]);
  o[6] = (short)f2bf(b[2]); o[7] = (short)f2bf(b[3]);
  *(short8*)(xb + i) = o;
}

// ---------------- kernel 3: bf16 GEMM, m97 structure ----------------
// 128x128 tile, BK=64, 4 waves (2x2), 4x4 frags of 16x16x32, global_load_lds w=16,
// XOR chunk swizzle: chunk kb of row r stored at position kb ^ (r&7) within 128B row.
static __device__ __forceinline__ void gload16(const void* g, void* l) {
  __builtin_amdgcn_global_load_lds(
      (const __attribute__((address_space(1))) unsigned*)g,
      (__attribute__((address_space(3))) unsigned*)l, 16, 0, 0);
}

__global__ __launch_bounds__(256) void gemm_k(const unsigned short* __restrict__ xb,
                                              const unsigned short* __restrict__ wt,
                                              const float* __restrict__ bias,
                                              float* __restrict__ out) {
  __shared__ unsigned short sA[128 * 64];
  __shared__ unsigned short sB[128 * 64];
  const int tid = threadIdx.x;
  const int lane = tid & 63;
  const int wv = tid >> 6;
  const int wm = wv >> 1, wn = wv & 1;
  const int nb = blockIdx.x % 86;
  const int mb = blockIdx.x / 86;
  const int m0 = mb * 128, n0 = nb * 128;

  // staging: thread covers 16B chunk; row = p*32 + tid/8, stored LDS pos = tid%8,
  // so source chunk kb = (tid%8) ^ (row&7) = (tid%8) ^ ((tid/8)&7)
  const int srow = tid >> 3;
  const int skb = (tid & 7) ^ (srow & 7);
  size_t aoff[4], boff[4];
#pragma unroll
  for (int p = 0; p < 4; ++p) {
    aoff[p] = (size_t)(m0 + p * 32 + srow) * KDIM + skb * 8;
    boff[p] = (size_t)(n0 + p * 32 + srow) * KDIM + skb * 8;
  }
  char* sAc = (char*)sA;
  char* sBc = (char*)sB;

  // frag reads: row = base + (lane&15), kb = ks*4 + (lane>>4), pos = kb ^ (row&7)
  const int r15 = lane & 15;
  const int swz0 = ((lane >> 4) ^ (lane & 7)) * 16;
  const int aRead = (wm * 64 + r15) * 128 + swz0;
  const int bRead = (wn * 64 + r15) * 128 + swz0;

  f32x4 acc[4][4];
#pragma unroll
  for (int i = 0; i < 4; ++i)
#pragma unroll
    for (int j = 0; j < 4; ++j) acc[i][j] = (f32x4){0.f, 0.f, 0.f, 0.f};

  for (int kt = 0; kt < KDIM / 64; ++kt) {
    const int k0 = kt * 64;
    __syncthreads();  // all waves done reading previous tile
#pragma unroll
    for (int p = 0; p < 4; ++p)
      gload16(xb + aoff[p] + k0, sAc + p * 4096 + tid * 16);
#pragma unroll
    for (int p = 0; p < 4; ++p)
      gload16(wt + boff[p] + k0, sBc + p * 4096 + tid * 16);
    __syncthreads();  // compiler emits vmcnt(0) drain before barrier -> LDS valid
#pragma unroll
    for (int ks = 0; ks < 2; ++ks) {
      const int sx = ks * 64;  // flips chunk bit 2 (kb ^= 4)
      short8 av[4], bv[4];
#pragma unroll
      for (int f = 0; f < 4; ++f)
        av[f] = *(const short8*)(sAc + ((aRead + f * 2048) ^ sx));
#pragma unroll
      for (int f = 0; f < 4; ++f)
        bv[f] = *(const short8*)(sBc + ((bRead + f * 2048) ^ sx));
#pragma unroll
      for (int i = 0; i < 4; ++i)
#pragma unroll
        for (int j = 0; j < 4; ++j)
          acc[i][j] = __builtin_amdgcn_mfma_f32_16x16x32_bf16(av[i], bv[j], acc[i][j], 0, 0, 0);
    }
  }

  // epilogue: C/D layout col = lane&15, row = (lane>>4)*4 + reg  (m89-verified)
  const int crow = m0 + wm * 64 + ((lane >> 4) * 4);
  const int ccol = n0 + wn * 64 + r15;
  float bv4[4];
#pragma unroll
  for (int j = 0; j < 4; ++j) bv4[j] = bias[ccol + j * 16];
#pragma unroll
  for (int i = 0; i < 4; ++i)
#pragma unroll
    for (int j = 0; j < 4; ++j)
#pragma unroll
      for (int e = 0; e < 4; ++e)
        out[(size_t)(crow + i * 16 + e) * TDIM + (ccol + j * 16)] = acc[i][j][e] + bv4[j];
}

extern "C" void kernel_launch(void* const* d_in, const int* in_sizes, int n_in,
                              void* d_out, int out_size, void* d_ws, size_t ws_size,
                              hipStream_t stream) {
  const float* x = (const float*)d_in[0];
  const unsigned* qw = (const unsigned*)d_in[1];
  const float* scales = (const float*)d_in[2];
  const float* zeros = (const float*)d_in[3];
  const float* bias = (const float*)d_in[4];
  float* out = (float*)d_out;

  unsigned short* wt = (unsigned short*)d_ws;                       // [TDIM][KDIM] bf16, 90.2MB
  unsigned short* xbf = (unsigned short*)((char*)d_ws + (size_t)TDIM * KDIM * 2);  // [BDIM][KDIM] bf16, 33.5MB

  // (KP/4)*TDIM / 256 = 5504 blocks exact
  dequant_k<<<5504, 256, 0, stream>>>(qw, scales, zeros, wt);
  // BDIM*KDIM/8/256 = 8192 blocks exact
  cvtx_k<<<8192, 256, 0, stream>>>(x, xbf);
  // (4096/128) * (11008/128) = 32*86 = 2752 blocks
  gemm_k<<<2752, 256, 0, stream>>>(xbf, wt, bias, out);
}

// Round 3
// 446.925 us; speedup vs baseline: 1.2832x; 1.2832x over previous
//
#include <hip/hip_runtime.h>
#include <hip/hip_bf16.h>
#include <stdint.h>

typedef short short8 __attribute__((ext_vector_type(8)));
typedef float f32x4 __attribute__((ext_vector_type(4)));
typedef float float4v __attribute__((ext_vector_type(4)));

#define KDIM 4096
#define TDIM 11008
#define BDIM 4096

// round-to-nearest-even f32 -> bf16 bits
static __device__ __forceinline__ unsigned short f2bf(float f) {
  unsigned u = __builtin_bit_cast(unsigned, f);
  u += 0x7FFFu + ((u >> 16) & 1u);
  return (unsigned short)(u >> 16);
}

// ---------------- kernel 1: dequant int4 -> bf16, transposed Wt[T][K] ----------------
__global__ __launch_bounds__(256) void dequant_k(const unsigned* __restrict__ qw,
                                                 const float* __restrict__ scales,
                                                 const float* __restrict__ zeros,
                                                 unsigned short* __restrict__ wt) {
  int idx = blockIdx.x * 256 + threadIdx.x;  // < 128*TDIM (grid exact)
  int rb = idx / TDIM;                       // 0..127
  int t = idx - rb * TDIM;
  int r0 = rb * 4;
  int g = rb >> 2;
  float s = scales[(size_t)g * TDIM + t];
  float z = zeros[(size_t)g * TDIM + t];
  float nzs = -z * s;
#pragma unroll
  for (int c = 0; c < 4; ++c) {
    unsigned q = qw[(size_t)(r0 + c) * TDIM + t];
    short8 o;
#pragma unroll
    for (int i = 0; i < 8; ++i) {
      float w = fmaf((float)((q >> (4 * i)) & 0xFu), s, nzs);
      o[i] = (short)f2bf(w);
    }
    *(short8*)(wt + (size_t)t * KDIM + (r0 + c) * 8) = o;
  }
}

// ---------------- kernel 2: x f32 -> bf16 ----------------
__global__ __launch_bounds__(256) void cvtx_k(const float* __restrict__ x,
                                              unsigned short* __restrict__ xb) {
  size_t i = ((size_t)blockIdx.x * 256 + threadIdx.x) * 8;
  float4v a = *(const float4v*)(x + i);
  float4v b = *(const float4v*)(x + i + 4);
  short8 o;
  o[0] = (short)f2bf(a[0]); o[1] = (short)f2bf(a[1]);
  o[2] = (short)f2bf(a[2]); o[3] = (short)f2bf(a[3]);
  o[4] = (short)f2bf(b[0]); o[5] = (short)f2bf(b[1]);
  o[6] = (short)f2bf(b[2]); o[7] = (short)f2bf(b[3]);
  *(short8*)(xb + i) = o;
}

// ---------------- kernel 3: 256x256 slice-pipelined bf16 GEMM ----------------
// 4 phases/iter (2 K-tiles). Slice = [256 rows][32 K] (16KB). Each phase reads
// EXACTLY one slice (12 ds_read_b128 + 32 MFMA) and restages that slice with the
// tile 2 ahead, issued AFTER the barrier (all waves' reads already issued -> no WAR
// race). vmcnt(12) at phase end keeps 3 slices in flight (counted, never 0).
static __device__ __forceinline__ void gload16(const void* g, void* l) {
  __builtin_amdgcn_global_load_lds(
      (const __attribute__((address_space(1))) unsigned*)g,
      (__attribute__((address_space(3))) unsigned*)l, 16, 0, 0);
}

#define ASM_BAR() asm volatile("s_barrier" ::: "memory")

__global__ __launch_bounds__(512, 2) void gemm3_k(const unsigned short* __restrict__ xb,
                                                  const unsigned short* __restrict__ wt,
                                                  const float* __restrict__ bias,
                                                  float* __restrict__ out) {
  __shared__ unsigned short sA[4 * 256 * 32];  // 64 KiB: [slice][row][32K], swizzled chunks
  __shared__ unsigned short sB[4 * 256 * 32];  // 64 KiB
  const int tid = threadIdx.x;
  const int lane = tid & 63;
  const int wid = tid >> 6;
  const int wm = wid >> 2, wn = wid & 3;  // 2 x 4 wave grid, wave output 128x64

  // XCD swizzle: nwg = 16*43 = 688 = 8*86
  const int bid = blockIdx.x;
  const int swz = (bid & 7) * 86 + (bid >> 3);
  const int mb = swz / 43, nb = swz % 43;
  const int m0 = mb * 256, n0 = nb * 256;

  char* sAc = (char*)sA;
  char* sBc = (char*)sB;

  // staging: chunks c = {tid, tid+512}; row = c>>2 (row0, row0+128), phys chunk pc = tid&3.
  // logical k-chunk kb = pc ^ (row&3) ^ ((row>>2)&3)  (identical for both rows: +128 preserves both terms)
  const int row0 = tid >> 2;
  const int pcs = tid & 3;
  const int kb = pcs ^ (row0 & 3) ^ ((row0 >> 2) & 3);
  const unsigned short* pA0 = xb + (size_t)(m0 + row0) * KDIM + kb * 8;
  const unsigned short* pA1 = pA0 + (size_t)128 * KDIM;
  const unsigned short* pB0 = wt + (size_t)(n0 + row0) * KDIM + kb * 8;
  const unsigned short* pB1 = pB0 + (size_t)128 * KDIM;
  const int dst0 = tid * 16, dst1 = 8192 + tid * 16;

  // stage slice SL (A and B) with global K-element offset koff
  auto stage = [&](int SL, int koff) {
    gload16(pA0 + koff, sAc + SL * 16384 + dst0);
    gload16(pA1 + koff, sAc + SL * 16384 + dst1);
    gload16(pB0 + koff, sBc + SL * 16384 + dst0);
    gload16(pB1 + koff, sBc + SL * 16384 + dst1);
  };

  // read addressing: frag row = base + f*16 + r15, k-chunk hi -> phys pc
  const int r15 = lane & 15;
  const int hi = lane >> 4;
  const int rpc = (hi ^ (r15 & 3) ^ ((r15 >> 2) & 3)) * 16;
  const int aRd = wm * 8192 + r15 * 64 + rpc;
  const int bRd = wn * 4096 + r15 * 64 + rpc;

  f32x4 acc[8][4];
#pragma unroll
  for (int i = 0; i < 8; ++i)
#pragma unroll
    for (int j = 0; j < 4; ++j) acc[i][j] = (f32x4){0.f, 0.f, 0.f, 0.f};

  auto phase = [&](int SL, int koff) {
    const char* pa = sAc + SL * 16384 + aRd;
    const char* pb = sBc + SL * 16384 + bRd;
    short8 a[8], b4[4];
#pragma unroll
    for (int f = 0; f < 8; ++f) a[f] = *(const short8*)(pa + f * 1024);
#pragma unroll
    for (int j = 0; j < 4; ++j) b4[j] = *(const short8*)(pb + j * 1024);
    ASM_BAR();  // all waves' ds_reads of slice SL are issued
    asm volatile("s_waitcnt lgkmcnt(0)" ::: "memory");
    __builtin_amdgcn_sched_barrier(0);
    stage(SL, koff);  // restage same slice, tile+2: write window provably dead
    __builtin_amdgcn_sched_barrier(0);
    __builtin_amdgcn_s_setprio(1);
#pragma unroll
    for (int f = 0; f < 8; ++f)
#pragma unroll
      for (int j = 0; j < 4; ++j)
        acc[f][j] = __builtin_amdgcn_mfma_f32_16x16x32_bf16(a[f], b4[j], acc[f][j], 0, 0, 0);
    __builtin_amdgcn_s_setprio(0);
    asm volatile("s_waitcnt vmcnt(12)" ::: "memory");  // retire slice staged 3 phases ago
    ASM_BAR();
  };

  // prologue: slices 0..3 <- tile0.ks0, tile0.ks1, tile1.ks0, tile1.ks1
  stage(0, 0);
  stage(1, 32);
  stage(2, 64);
  stage(3, 96);
  asm volatile("s_waitcnt vmcnt(0)" ::: "memory");
  ASM_BAR();

  for (int it = 0; it < 32; ++it) {
    const int t0 = (2 * it + 2) & 63;  // wrap: it=31 stages dummy (never read)
    const int t1 = (2 * it + 3) & 63;
    phase(0, t0 * 64);
    phase(1, t0 * 64 + 32);
    phase(2, t1 * 64);
    phase(3, t1 * 64 + 32);
  }

  // epilogue: C layout col=lane&15, row=(lane>>4)*4+e (R1-verified convention)
  const int orow = m0 + wm * 128 + hi * 4;
  const int ocol = n0 + wn * 64 + r15;
  float bb[4];
#pragma unroll
  for (int j = 0; j < 4; ++j) bb[j] = bias[ocol + j * 16];
#pragma unroll
  for (int i = 0; i < 8; ++i)
#pragma unroll
    for (int j = 0; j < 4; ++j)
#pragma unroll
      for (int e = 0; e < 4; ++e)
        out[(size_t)(orow + i * 16 + e) * TDIM + (ocol + j * 16)] = acc[i][j][e] + bb[j];
}

extern "C" void kernel_launch(void* const* d_in, const int* in_sizes, int n_in,
                              void* d_out, int out_size, void* d_ws, size_t ws_size,
                              hipStream_t stream) {
  const float* x = (const float*)d_in[0];
  const unsigned* qw = (const unsigned*)d_in[1];
  const float* scales = (const float*)d_in[2];
  const float* zeros = (const float*)d_in[3];
  const float* bias = (const float*)d_in[4];
  float* out = (float*)d_out;

  unsigned short* wt = (unsigned short*)d_ws;  // [TDIM][KDIM] bf16
  unsigned short* xbf = (unsigned short*)((char*)d_ws + (size_t)TDIM * KDIM * 2);  // [BDIM][KDIM] bf16

  dequant_k<<<5504, 256, 0, stream>>>(qw, scales, zeros, wt);
  cvtx_k<<<8192, 256, 0, stream>>>(x, xbf);
  gemm3_k<<<688, 512, 0, stream>>>(xbf, wt, bias, out);
}

// Round 4
// 444.208 us; speedup vs baseline: 1.2910x; 1.0061x over previous
//
#include <hip/hip_runtime.h>
#include <hip/hip_bf16.h>
#include <stdint.h>

typedef short short8 __attribute__((ext_vector_type(8)));
typedef float f32x4 __attribute__((ext_vector_type(4)));
typedef float float4v __attribute__((ext_vector_type(4)));

#define KDIM 4096
#define TDIM 11008
#define BDIM 4096

static __device__ __forceinline__ unsigned short f2bf(float f) {
  unsigned u = __builtin_bit_cast(unsigned, f);
  u += 0x7FFFu + ((u >> 16) & 1u);
  return (unsigned short)(u >> 16);
}

// ---------------- kernel 1: dequant int4 -> bf16, transposed Wt[T][K] ----------------
__global__ __launch_bounds__(256) void dequant_k(const unsigned* __restrict__ qw,
                                                 const float* __restrict__ scales,
                                                 const float* __restrict__ zeros,
                                                 unsigned short* __restrict__ wt) {
  int idx = blockIdx.x * 256 + threadIdx.x;
  int rb = idx / TDIM;
  int t = idx - rb * TDIM;
  int r0 = rb * 4;
  int g = rb >> 2;
  float s = scales[(size_t)g * TDIM + t];
  float z = zeros[(size_t)g * TDIM + t];
  float nzs = -z * s;
#pragma unroll
  for (int c = 0; c < 4; ++c) {
    unsigned q = qw[(size_t)(r0 + c) * TDIM + t];
    short8 o;
#pragma unroll
    for (int i = 0; i < 8; ++i) {
      float w = fmaf((float)((q >> (4 * i)) & 0xFu), s, nzs);
      o[i] = (short)f2bf(w);
    }
    *(short8*)(wt + (size_t)t * KDIM + (r0 + c) * 8) = o;
  }
}

// ---------------- kernel 2: x f32 -> bf16 ----------------
__global__ __launch_bounds__(256) void cvtx_k(const float* __restrict__ x,
                                              unsigned short* __restrict__ xb) {
  size_t i = ((size_t)blockIdx.x * 256 + threadIdx.x) * 8;
  float4v a = *(const float4v*)(x + i);
  float4v b = *(const float4v*)(x + i + 4);
  short8 o;
  o[0] = (short)f2bf(a[0]); o[1] = (short)f2bf(a[1]);
  o[2] = (short)f2bf(a[2]); o[3] = (short)f2bf(a[3]);
  o[4] = (short)f2bf(b[0]); o[5] = (short)f2bf(b[1]);
  o[6] = (short)f2bf(b[2]); o[7] = (short)f2bf(b[3]);
  *(short8*)(xb + i) = o;
}

// ---------------- kernel 3: 256x256 4-phase/tile bf16 GEMM, 128B rows + 3-bit XOR ----
static __device__ __forceinline__ void gload16(const void* g, void* l) {
  __builtin_amdgcn_global_load_lds(
      (const __attribute__((address_space(1))) unsigned*)g,
      (__attribute__((address_space(3))) unsigned*)l, 16, 0, 0);
}

#define ASM_BAR() asm volatile("s_barrier" ::: "memory")
#define LGKM0() do { asm volatile("s_waitcnt lgkmcnt(0)" ::: "memory"); __builtin_amdgcn_sched_barrier(0); } while (0)
#define VM6() asm volatile("s_waitcnt vmcnt(6)" ::: "memory")
#define SB0() __builtin_amdgcn_sched_barrier(0)
#define MFMA16(FB, JB, BV)                                                              \
  __builtin_amdgcn_s_setprio(1);                                                        \
  _Pragma("unroll") for (int f = 0; f < 4; ++f) _Pragma("unroll") for (int j = 0; j < 2; ++j) { \
    f32x4 c = acc[FB + f][JB + j];                                                      \
    c = __builtin_amdgcn_mfma_f32_16x16x32_bf16(av[f][0], BV[j][0], c, 0, 0, 0);        \
    c = __builtin_amdgcn_mfma_f32_16x16x32_bf16(av[f][1], BV[j][1], c, 0, 0, 0);        \
    acc[FB + f][JB + j] = c;                                                            \
  }                                                                                     \
  __builtin_amdgcn_s_setprio(0)

__global__ __launch_bounds__(512, 2) void gemm4_k(const unsigned short* __restrict__ xb,
                                                  const unsigned short* __restrict__ wt,
                                                  const float* __restrict__ bias,
                                                  float* __restrict__ out) {
  __shared__ unsigned short sA[2 * 256 * 64];  // 64 KiB: [buf][row][64K], 128B rows
  __shared__ unsigned short sB[2 * 256 * 64];  // 64 KiB
  const int tid = threadIdx.x;
  const int lane = tid & 63;
  const int wid = tid >> 6;
  const int wm = wid >> 2, wn = wid & 3;

  // XCD swizzle: nwg = 16*43 = 688 = 8*86
  const int bid = blockIdx.x;
  const int swz = (bid & 7) * 86 + (bid >> 3);
  const int mb = swz / 43, nb = swz % 43;
  const int m0 = mb * 256, n0 = nb * 256;

  char* sAc = (char*)sA;
  char* sBc = (char*)sB;

  // ---- staging precompute (R1-proven 3-bit XOR; dest linear per wave) ----
  const int sr = tid >> 3;                       // 0..63 (load1 adds 128 rows)
  const int pcb = (tid & 7) * 16;                // phys chunk byte
  const int kbel = ((tid & 7) ^ (sr & 7)) * 8;   // logical k-chunk (elements)
  const int grB = (sr >> 5) * 64 + (sr & 31);    // B-set row base (QN=0)
  const unsigned short* srcA = xb + (size_t)m0 * KDIM + kbel;
  const unsigned short* srcB = wt + (size_t)n0 * KDIM + kbel;

  auto stage2 = [&](const unsigned short* src, char* dst, int gr, int koff) {
    gload16(src + (size_t)gr * KDIM + koff, dst + gr * 128);
    gload16(src + (size_t)(gr + 128) * KDIM + koff, dst + (gr + 128) * 128);
  };
  // A-set QM of tile kt -> buffer b ; B-set QN of tile kt -> buffer b
  auto stA = [&](int b, int QM, int kt) { stage2(srcA, sAc + b * 32768 + pcb, QM * 64 + sr, kt * 64); };
  auto stB = [&](int b, int QN, int kt) { stage2(srcB, sBc + b * 32768 + pcb, QN * 32 + grB, kt * 64); };

  // ---- read addressing: phys = (ks*4+hi) ^ (r15&7), 128B rows ----
  const int r15 = lane & 15;
  const int hi = lane >> 4;
  const int sw0 = ((hi) ^ (r15 & 7)) * 16;
  const int sw1 = ((4 + hi) ^ (r15 & 7)) * 16;
  const char* aR[2] = {sAc + (wm * 128 + r15) * 128, sAc + 32768 + (wm * 128 + r15) * 128};
  const char* bR[2] = {sBc + (wn * 64 + r15) * 128, sBc + 32768 + (wn * 64 + r15) * 128};

  f32x4 acc[8][4];
#pragma unroll
  for (int i = 0; i < 8; ++i)
#pragma unroll
    for (int j = 0; j < 4; ++j) acc[i][j] = (f32x4){0.f, 0.f, 0.f, 0.f};

  short8 av[4][2], bv0[2][2], bv1[2][2];

  // prologue: tile0 full + A0(1) + B1(1); keep last 2 sets outstanding
  stA(0, 0, 0); stB(0, 0, 0); stB(0, 1, 0); stA(0, 1, 0);
  stA(1, 0, 1); stB(1, 1, 1);
  asm volatile("s_waitcnt vmcnt(4)" ::: "memory");
  ASM_BAR();

  auto tile4 = [&](int buf, int T) {
    const char* ab = aR[buf];
    const char* bb = bR[buf];
    const int obuf = buf ^ 1;
    const int k1 = ((T + 1) & 63), k2 = ((T + 2) & 63);
    // ph0 (Q00): read av(QM=0)+bv0; stage B0(T+1)->obuf
#pragma unroll
    for (int f = 0; f < 4; ++f) {
      av[f][0] = *(const short8*)(ab + f * 2048 + sw0);
      av[f][1] = *(const short8*)(ab + f * 2048 + sw1);
    }
#pragma unroll
    for (int j = 0; j < 2; ++j) {
      bv0[j][0] = *(const short8*)(bb + j * 2048 + sw0);
      bv0[j][1] = *(const short8*)(bb + j * 2048 + sw1);
    }
    ASM_BAR(); LGKM0();
    stB(obuf, 0, k1); SB0();
    MFMA16(0, 0, bv0);
    VM6(); ASM_BAR();
    // ph1 (Q01): read bv1; stage A1(T+1)->obuf  (av cached)
#pragma unroll
    for (int j = 0; j < 2; ++j) {
      bv1[j][0] = *(const short8*)(bb + 4096 + j * 2048 + sw0);
      bv1[j][1] = *(const short8*)(bb + 4096 + j * 2048 + sw1);
    }
    ASM_BAR(); LGKM0();
    stA(obuf, 1, k1); SB0();
    MFMA16(0, 2, bv1);
    VM6(); ASM_BAR();
    // ph2 (Q11): read av(QM=1); stage A0(T+2)->buf  (bv1 cached)
#pragma unroll
    for (int f = 0; f < 4; ++f) {
      av[f][0] = *(const short8*)(ab + 8192 + f * 2048 + sw0);
      av[f][1] = *(const short8*)(ab + 8192 + f * 2048 + sw1);
    }
    ASM_BAR(); LGKM0();
    stA(buf, 0, k2); SB0();
    MFMA16(4, 2, bv1);
    VM6(); ASM_BAR();
    // ph3 (Q10): re-read bv0; stage B1(T+2)->buf
#pragma unroll
    for (int j = 0; j < 2; ++j) {
      bv0[j][0] = *(const short8*)(bb + j * 2048 + sw0);
      bv0[j][1] = *(const short8*)(bb + j * 2048 + sw1);
    }
    ASM_BAR(); LGKM0();
    stB(buf, 1, k2); SB0();
    MFMA16(4, 0, bv0);
    VM6(); ASM_BAR();
  };

  for (int u = 0; u < 32; ++u) {
    tile4(0, 2 * u);
    tile4(1, 2 * u + 1);
  }

  // epilogue: C layout col=lane&15, row=(lane>>4)*4+e
  const int orow = m0 + wm * 128 + hi * 4;
  const int ocol = n0 + wn * 64 + r15;
  float bb4[4];
#pragma unroll
  for (int j = 0; j < 4; ++j) bb4[j] = bias[ocol + j * 16];
#pragma unroll
  for (int i = 0; i < 8; ++i)
#pragma unroll
    for (int j = 0; j < 4; ++j)
#pragma unroll
      for (int e = 0; e < 4; ++e)
        out[(size_t)(orow + i * 16 + e) * TDIM + (ocol + j * 16)] = acc[i][j][e] + bb4[j];
}

extern "C" void kernel_launch(void* const* d_in, const int* in_sizes, int n_in,
                              void* d_out, int out_size, void* d_ws, size_t ws_size,
                              hipStream_t stream) {
  const float* x = (const float*)d_in[0];
  const unsigned* qw = (const unsigned*)d_in[1];
  const float* scales = (const float*)d_in[2];
  const float* zeros = (const float*)d_in[3];
  const float* bias = (const float*)d_in[4];
  float* out = (float*)d_out;

  unsigned short* wt = (unsigned short*)d_ws;
  unsigned short* xbf = (unsigned short*)((char*)d_ws + (size_t)TDIM * KDIM * 2);

  dequant_k<<<5504, 256, 0, stream>>>(qw, scales, zeros, wt);
  cvtx_k<<<8192, 256, 0, stream>>>(x, xbf);
  gemm4_k<<<688, 512, 0, stream>>>(xbf, wt, bias, out);
}